// Round 1
// baseline (184.718 us; speedup 1.0000x reference)
//
#include <hip/hip_runtime.h>
#include <hip/hip_bf16.h>
#include <stdint.h>

typedef __bf16 bf16_t;
typedef __bf16 bf16x8 __attribute__((ext_vector_type(8)));
typedef __bf16 bf16x4 __attribute__((ext_vector_type(4)));
typedef float  f32x4  __attribute__((ext_vector_type(4)));

#define LOG2E 1.44269504088896340736f

// ---------------- helpers ----------------

__device__ __forceinline__ void glds16(const bf16_t* g, bf16_t* l) {
  // async global->LDS, 16B per lane; LDS dest must be wave-uniform base (+lane*16 implicit)
  __builtin_amdgcn_global_load_lds(
      (const __attribute__((address_space(1))) void*)(g),
      (__attribute__((address_space(3))) void*)(l), 16, 0, 0);
}

__device__ __forceinline__ float grp_max(float v) {
#pragma unroll
  for (int off = 1; off < 16; off <<= 1) v = fmaxf(v, __shfl_xor(v, off, 64));
  return v;
}
__device__ __forceinline__ float grp_sum(float v) {
#pragma unroll
  for (int off = 1; off < 16; off <<= 1) v += __shfl_xor(v, off, 64);
  return v;
}

// ---------------- cast x: f32 -> bf16 ----------------

__global__ __launch_bounds__(256) void cast_x_kernel(const float* __restrict__ x,
                                                     bf16_t* __restrict__ xb) {
  int i = (blockIdx.x * 256 + threadIdx.x) * 4;
  float4 v = *reinterpret_cast<const float4*>(x + i);
  bf16x4 o = { (bf16_t)v.x, (bf16_t)v.y, (bf16_t)v.z, (bf16_t)v.w };
  *reinterpret_cast<bf16x4*>(xb + i) = o;
}

// ---------------- transpose+cast W[1024][1024] f32 -> Wt[n][k] bf16 ----------------

__global__ __launch_bounds__(256) void transpose_w_kernel(
    const float* __restrict__ W0, const float* __restrict__ W1,
    const float* __restrict__ W2, const float* __restrict__ W3,
    bf16_t* __restrict__ T0, bf16_t* __restrict__ T1,
    bf16_t* __restrict__ T2, bf16_t* __restrict__ T3) {
  const float* W = blockIdx.z == 0 ? W0 : blockIdx.z == 1 ? W1 : blockIdx.z == 2 ? W2 : W3;
  bf16_t*      T = blockIdx.z == 0 ? T0 : blockIdx.z == 1 ? T1 : blockIdx.z == 2 ? T2 : T3;
  __shared__ float tile[64][65];
  int tid = threadIdx.x;
  int k0 = blockIdx.y * 64, n0 = blockIdx.x * 64;
  int rr = tid >> 4, cc = (tid & 15) * 4;
#pragma unroll
  for (int p = 0; p < 4; ++p) {
    float4 v = *reinterpret_cast<const float4*>(W + (size_t)(k0 + p * 16 + rr) * 1024 + n0 + cc);
    tile[p * 16 + rr][cc + 0] = v.x; tile[p * 16 + rr][cc + 1] = v.y;
    tile[p * 16 + rr][cc + 2] = v.z; tile[p * 16 + rr][cc + 3] = v.w;
  }
  __syncthreads();
#pragma unroll
  for (int p = 0; p < 4; ++p) {
    bf16x4 o;
#pragma unroll
    for (int i2 = 0; i2 < 4; ++i2) o[i2] = (bf16_t)tile[cc + i2][p * 16 + rr];
    *reinterpret_cast<bf16x4*>(T + (size_t)(n0 + p * 16 + rr) * 1024 + k0 + cc) = o;
  }
}

// ---------------- shared GEMM main loop: C[128x128] over K=1024 ----------------
// A [4096][1024] bf16 row-major; Wt [1024(n)][1024(k)] bf16 row-major.
// 4 waves in 2x2; each wave 64x64 = 4x4 frags of 16x16x32.

__device__ __forceinline__ void gemm_tile(const bf16_t* __restrict__ A,
                                          const bf16_t* __restrict__ Wt,
                                          int m0, int n0,
                                          bf16_t* Al, bf16_t* Bl,
                                          f32x4 acc[4][4]) {
  int tid = threadIdx.x;
  int w = tid >> 6, lane = tid & 63, g = lane >> 4, t = lane & 15;
  int wr = w >> 1, wc = w & 1;
#pragma unroll
  for (int m = 0; m < 4; ++m)
#pragma unroll
    for (int n = 0; n < 4; ++n) acc[m][n] = (f32x4){0.f, 0.f, 0.f, 0.f};

  for (int k0 = 0; k0 < 1024; k0 += 32) {
    // stage A-tile [128][32] and B-tile [128(n)][32(k)] via global_load_lds (linear LDS)
#pragma unroll
    for (int r2 = 0; r2 < 2; ++r2) {
      int cb = r2 * 256 + w * 64;       // wave-uniform chunk base (16B chunks)
      int cidx = cb + lane;             // this lane's chunk
      int row = cidx >> 2, cc = cidx & 3;
      glds16(A  + (size_t)(m0 + row) * 1024 + k0 + cc * 8, Al + (size_t)cb * 8);
      glds16(Wt + (size_t)(n0 + row) * 1024 + k0 + cc * 8, Bl + (size_t)cb * 8);
    }
    __syncthreads();
    bf16x8 af[4], bfv[4];
#pragma unroll
    for (int m = 0; m < 4; ++m)
      af[m] = *reinterpret_cast<const bf16x8*>(Al + (wr * 64 + m * 16 + t) * 32 + g * 8);
#pragma unroll
    for (int n = 0; n < 4; ++n)
      bfv[n] = *reinterpret_cast<const bf16x8*>(Bl + (wc * 64 + n * 16 + t) * 32 + g * 8);
#pragma unroll
    for (int m = 0; m < 4; ++m)
#pragma unroll
      for (int n = 0; n < 4; ++n)
        acc[m][n] = __builtin_amdgcn_mfma_f32_16x16x32_bf16(af[m], bfv[n], acc[m][n], 0, 0, 0);
    __syncthreads();
  }
}

// ---------------- QKV projection GEMM (z selects Q/K/V) ----------------
// z=0: Q = (x@Wq + bq) * 0.125 -> bf16 [4096][1024]
// z=1: K =  x@Wk + bk          -> bf16 [4096][1024]
// z=2: V =  x@Wv + bv          -> bf16 transposed Vt[b][n][s]  (b=row>>11, s=row&2047)

__global__ __launch_bounds__(256) void gemm_qkv_kernel(
    const bf16_t* __restrict__ A,
    const bf16_t* __restrict__ wtq, const bf16_t* __restrict__ wtk, const bf16_t* __restrict__ wtv,
    const float* __restrict__ bq, const float* __restrict__ bk, const float* __restrict__ bv,
    bf16_t* __restrict__ Qo, bf16_t* __restrict__ Ko, bf16_t* __restrict__ Vt) {
  __shared__ bf16_t Al[128 * 32];
  __shared__ bf16_t Bl[128 * 32];
  int z = blockIdx.z;
  const bf16_t* Wt  = z == 0 ? wtq : z == 1 ? wtk : wtv;
  const float* bias = z == 0 ? bq  : z == 1 ? bk  : bv;
  int m0 = blockIdx.x * 128, n0 = blockIdx.y * 128;
  f32x4 acc[4][4];
  gemm_tile(A, Wt, m0, n0, Al, Bl, acc);

  int tid = threadIdx.x, w = tid >> 6, lane = tid & 63, g = lane >> 4, t = lane & 15;
  int wr = w >> 1, wc = w & 1;
#pragma unroll
  for (int n = 0; n < 4; ++n) {
    int col = n0 + wc * 64 + n * 16 + t;
    float bv_ = bias[col];
#pragma unroll
    for (int m = 0; m < 4; ++m) {
      int row0 = m0 + wr * 64 + m * 16 + g * 4;
      if (z == 2) {
        bf16x4 o;
#pragma unroll
        for (int r = 0; r < 4; ++r) o[r] = (bf16_t)(acc[m][n][r] + bv_);
        *reinterpret_cast<bf16x4*>(Vt + ((size_t)(row0 >> 11) << 21) + (size_t)col * 2048 +
                                   (row0 & 2047)) = o;
      } else {
        float sc = (z == 0) ? 0.125f : 1.0f;   // fold 1/sqrt(KD) into Q (exact pow2)
        bf16_t* O = (z == 0) ? Qo : Ko;
#pragma unroll
        for (int r = 0; r < 4; ++r)
          O[(size_t)(row0 + r) * 1024 + col] = (bf16_t)((acc[m][n][r] + bv_) * sc);
      }
    }
  }
}

// ---------------- output projection GEMM -> fp32 d_out ----------------

__global__ __launch_bounds__(256) void gemm_out_kernel(
    const bf16_t* __restrict__ A, const bf16_t* __restrict__ Wt,
    const float* __restrict__ bias, float* __restrict__ out) {
  __shared__ bf16_t Al[128 * 32];
  __shared__ bf16_t Bl[128 * 32];
  int m0 = blockIdx.x * 128, n0 = blockIdx.y * 128;
  f32x4 acc[4][4];
  gemm_tile(A, Wt, m0, n0, Al, Bl, acc);

  int tid = threadIdx.x, w = tid >> 6, lane = tid & 63, g = lane >> 4, t = lane & 15;
  int wr = w >> 1, wc = w & 1;
#pragma unroll
  for (int n = 0; n < 4; ++n) {
    int col = n0 + wc * 64 + n * 16 + t;
    float bv_ = bias[col];
#pragma unroll
    for (int m = 0; m < 4; ++m) {
      int row0 = m0 + wr * 64 + m * 16 + g * 4;
#pragma unroll
      for (int r = 0; r < 4; ++r)
        out[(size_t)(row0 + r) * 1024 + col] = acc[m][n][r] + bv_;
    }
  }
}

// ---------------- flash attention ----------------
// grid (S/64, H, B); 4 waves x 16 q-rows; KV tiles of 64 keys.
// Q pre-scaled by 1/8. K [B,S,H*KD]; Vt [B, H*KD, S]; out Ao [B,S,H*KD] bf16.

__global__ __launch_bounds__(256) void attn_kernel(
    const bf16_t* __restrict__ Q, const bf16_t* __restrict__ K,
    const bf16_t* __restrict__ Vt, bf16_t* __restrict__ Ao) {
  __shared__ bf16_t Kl[64 * 72];     // padded rows: 72 elems = 144B (16B-aligned, spread)
  __shared__ bf16_t Vl[64 * 72];
  __shared__ bf16_t Pl[4][16 * 72];
  int tid = threadIdx.x, w = tid >> 6, lane = tid & 63, g = lane >> 4, t = lane & 15;
  int qbase = blockIdx.x * 64, h = blockIdx.y, b = blockIdx.z;

  const bf16_t* qp = Q + (size_t)(b * 2048 + qbase + w * 16 + t) * 1024 + h * 64;
  bf16x8 qf[2];
#pragma unroll
  for (int kk = 0; kk < 2; ++kk)
    qf[kk] = *reinterpret_cast<const bf16x8*>(qp + kk * 32 + g * 8);

  f32x4 o[4];
  float mrun[4], lrun[4];
#pragma unroll
  for (int c = 0; c < 4; ++c) o[c] = (f32x4){0.f, 0.f, 0.f, 0.f};
#pragma unroll
  for (int r = 0; r < 4; ++r) { mrun[r] = -1e30f; lrun[r] = 0.f; }

  const bf16_t* Kbase = K + (size_t)b * 2048 * 1024 + h * 64;
  const bf16_t* Vbase = Vt + ((size_t)b << 21) + (size_t)h * 64 * 2048;

  for (int jt = 0; jt < 32; ++jt) {
    int jbase = jt * 64;
    // stage K tile [64 keys][64 f] and V tile [64 f][64 keys] (reg-staged, padded LDS)
#pragma unroll
    for (int r2 = 0; r2 < 2; ++r2) {
      int cidx = r2 * 256 + tid;
      int row = cidx >> 3, cc = cidx & 7;
      bf16x8 kv = *reinterpret_cast<const bf16x8*>(Kbase + (size_t)(jbase + row) * 1024 + cc * 8);
      *reinterpret_cast<bf16x8*>(Kl + row * 72 + cc * 8) = kv;
      bf16x8 vv = *reinterpret_cast<const bf16x8*>(Vbase + (size_t)row * 2048 + jbase + cc * 8);
      *reinterpret_cast<bf16x8*>(Vl + row * 72 + cc * 8) = vv;
    }
    __syncthreads();

    // QK^T: s[c] holds S[4g+r][c*16+t] (pre-scaled via Q)
    f32x4 s[4];
#pragma unroll
    for (int c = 0; c < 4; ++c) {
      s[c] = (f32x4){0.f, 0.f, 0.f, 0.f};
#pragma unroll
      for (int kk = 0; kk < 2; ++kk) {
        bf16x8 kb = *reinterpret_cast<const bf16x8*>(Kl + (c * 16 + t) * 72 + kk * 32 + g * 8);
        s[c] = __builtin_amdgcn_mfma_f32_16x16x32_bf16(qf[kk], kb, s[c], 0, 0, 0);
      }
    }

    // online softmax (rows 4g+r live in lane-group g; reduce over t within group)
    float corr[4];
#pragma unroll
    for (int r = 0; r < 4; ++r) {
      float tm = grp_max(fmaxf(fmaxf(s[0][r], s[1][r]), fmaxf(s[2][r], s[3][r])));
      float mn = fmaxf(mrun[r], tm);
      corr[r] = __builtin_amdgcn_exp2f((mrun[r] - mn) * LOG2E);
      mrun[r] = mn;
    }
#pragma unroll
    for (int c = 0; c < 4; ++c)
#pragma unroll
      for (int r = 0; r < 4; ++r)
        s[c][r] = __builtin_amdgcn_exp2f((s[c][r] - mrun[r]) * LOG2E);
#pragma unroll
    for (int r = 0; r < 4; ++r) {
      float rs = grp_sum(s[0][r] + s[1][r] + s[2][r] + s[3][r]);
      lrun[r] = lrun[r] * corr[r] + rs;
    }
#pragma unroll
    for (int c = 0; c < 4; ++c) {
      f32x4 oc = o[c];
#pragma unroll
      for (int r = 0; r < 4; ++r) oc[r] *= corr[r];
      o[c] = oc;
    }

    // P -> LDS (bf16), then read back as A-fragments (same wave; DS is in-order per wave)
#pragma unroll
    for (int c = 0; c < 4; ++c)
#pragma unroll
      for (int r = 0; r < 4; ++r)
        Pl[w][(g * 4 + r) * 72 + c * 16 + t] = (bf16_t)s[c][r];
    asm volatile("s_waitcnt lgkmcnt(0)" ::: "memory");

    // PV
#pragma unroll
    for (int kk = 0; kk < 2; ++kk) {
      bf16x8 pa = *reinterpret_cast<const bf16x8*>(&Pl[w][t * 72 + kk * 32 + g * 8]);
#pragma unroll
      for (int c = 0; c < 4; ++c) {
        bf16x8 vb = *reinterpret_cast<const bf16x8*>(Vl + (c * 16 + t) * 72 + kk * 32 + g * 8);
        o[c] = __builtin_amdgcn_mfma_f32_16x16x32_bf16(pa, vb, o[c], 0, 0, 0);
      }
    }
    __syncthreads();
  }

  // epilogue: divide by l, store bf16
#pragma unroll
  for (int r = 0; r < 4; ++r) lrun[r] = 1.f / lrun[r];
  size_t obase = (size_t)(b * 2048 + qbase + w * 16 + g * 4) * 1024 + h * 64;
#pragma unroll
  for (int c = 0; c < 4; ++c)
#pragma unroll
    for (int r = 0; r < 4; ++r)
      Ao[obase + (size_t)r * 1024 + c * 16 + t] = (bf16_t)(o[c][r] * lrun[r]);
}

// ---------------- launch ----------------

extern "C" void kernel_launch(void* const* d_in, const int* in_sizes, int n_in,
                              void* d_out, int out_size, void* d_ws, size_t ws_size,
                              hipStream_t stream) {
  const float* x  = (const float*)d_in[0];
  const float* Wq = (const float*)d_in[1];
  const float* bq = (const float*)d_in[2];
  const float* Wk = (const float*)d_in[3];
  const float* bk = (const float*)d_in[4];
  const float* Wv = (const float*)d_in[5];
  const float* bv = (const float*)d_in[6];
  const float* Wo = (const float*)d_in[7];
  const float* bo = (const float*)d_in[8];
  float* out = (float*)d_out;
  char* ws = (char*)d_ws;

  bf16_t* xb  = (bf16_t*)(ws);
  bf16_t* wqt = (bf16_t*)(ws + 8388608);
  bf16_t* wkt = (bf16_t*)(ws + 8388608 + 2097152);
  bf16_t* wvt = (bf16_t*)(ws + 8388608 + 2 * 2097152);
  bf16_t* wot = (bf16_t*)(ws + 8388608 + 3 * 2097152);
  bf16_t* Qs  = (bf16_t*)(ws + 16777216);
  bf16_t* Kb  = (bf16_t*)(ws + 16777216 + 8388608);
  bf16_t* Vt  = (bf16_t*)(ws + 16777216 + 2 * 8388608);
  bf16_t* Ao  = (bf16_t*)(ws + 16777216 + 3 * 8388608);

  cast_x_kernel<<<4096, 256, 0, stream>>>(x, xb);
  transpose_w_kernel<<<dim3(16, 16, 4), 256, 0, stream>>>(Wq, Wk, Wv, Wo, wqt, wkt, wvt, wot);
  gemm_qkv_kernel<<<dim3(32, 8, 3), 256, 0, stream>>>(xb, wqt, wkt, wvt, bq, bk, bv, Qs, Kb, Vt);
  attn_kernel<<<dim3(32, 16, 2), 256, 0, stream>>>(Qs, Kb, Vt, Ao);
  gemm_out_kernel<<<dim3(32, 8), 256, 0, stream>>>(Ao, wot, bo, out);
}

// Round 4
// 127.531 us; speedup vs baseline: 1.4484x; 1.4484x over previous
//
#include <hip/hip_runtime.h>
#include <hip/hip_bf16.h>
#include <stdint.h>

typedef __bf16 bf16_t;
typedef __bf16 bf16x8 __attribute__((ext_vector_type(8)));
typedef __bf16 bf16x4 __attribute__((ext_vector_type(4)));
typedef float  f32x4  __attribute__((ext_vector_type(4)));

#define LOG2E 1.44269504088896340736f

// ---------------- helpers ----------------

__device__ __forceinline__ void glds16(const bf16_t* g, bf16_t* l) {
  __builtin_amdgcn_global_load_lds(
      (const __attribute__((address_space(1))) void*)(g),
      (__attribute__((address_space(3))) void*)(l), 16, 0, 0);
}

// XOR-swizzled LDS element index for 128B rows: byte ^= (row&7)<<4.
// Involution + bijective within each row => read(swzi) of write(swzi) is identity.
__device__ __forceinline__ int swzi(int row, int cbyte) {
  return row * 64 + ((cbyte ^ ((row & 7) << 4)) >> 1);
}

// ---------------- cast x: f32 -> bf16 ----------------

__global__ __launch_bounds__(256) void cast_x_kernel(const float* __restrict__ x,
                                                     bf16_t* __restrict__ xb) {
  int i = (blockIdx.x * 256 + threadIdx.x) * 4;
  float4 v = *reinterpret_cast<const float4*>(x + i);
  bf16x4 o = { (bf16_t)v.x, (bf16_t)v.y, (bf16_t)v.z, (bf16_t)v.w };
  *reinterpret_cast<bf16x4*>(xb + i) = o;
}

// ---------------- transpose+cast W[1024][1024] f32 -> Wt[n][k] bf16 ----------------

__global__ __launch_bounds__(256) void transpose_w_kernel(
    const float* __restrict__ W0, const float* __restrict__ W1,
    const float* __restrict__ W2, const float* __restrict__ W3,
    bf16_t* __restrict__ T0, bf16_t* __restrict__ T1,
    bf16_t* __restrict__ T2, bf16_t* __restrict__ T3) {
  const float* W = blockIdx.z == 0 ? W0 : blockIdx.z == 1 ? W1 : blockIdx.z == 2 ? W2 : W3;
  bf16_t*      T = blockIdx.z == 0 ? T0 : blockIdx.z == 1 ? T1 : blockIdx.z == 2 ? T2 : T3;
  __shared__ float tile[64][65];
  int tid = threadIdx.x;
  int k0 = blockIdx.y * 64, n0 = blockIdx.x * 64;
  int rr = tid >> 4, cc = (tid & 15) * 4;
#pragma unroll
  for (int p = 0; p < 4; ++p) {
    float4 v = *reinterpret_cast<const float4*>(W + (size_t)(k0 + p * 16 + rr) * 1024 + n0 + cc);
    tile[p * 16 + rr][cc + 0] = v.x; tile[p * 16 + rr][cc + 1] = v.y;
    tile[p * 16 + rr][cc + 2] = v.z; tile[p * 16 + rr][cc + 3] = v.w;
  }
  __syncthreads();
#pragma unroll
  for (int p = 0; p < 4; ++p) {
    bf16x4 o;
#pragma unroll
    for (int i2 = 0; i2 < 4; ++i2) o[i2] = (bf16_t)tile[cc + i2][p * 16 + rr];
    *reinterpret_cast<bf16x4*>(T + (size_t)(n0 + p * 16 + rr) * 1024 + k0 + cc) = o;
  }
}

// ---------------- shared GEMM main loop: C[128x128] over K=1024 ----------------

__device__ __forceinline__ void gemm_tile(const bf16_t* __restrict__ A,
                                          const bf16_t* __restrict__ Wt,
                                          int m0, int n0,
                                          bf16_t* Al, bf16_t* Bl,
                                          f32x4 acc[4][4]) {
  int tid = threadIdx.x;
  int w = tid >> 6, lane = tid & 63, g = lane >> 4, t = lane & 15;
  int wr = w >> 1, wc = w & 1;
#pragma unroll
  for (int m = 0; m < 4; ++m)
#pragma unroll
    for (int n = 0; n < 4; ++n) acc[m][n] = (f32x4){0.f, 0.f, 0.f, 0.f};

  for (int k0 = 0; k0 < 1024; k0 += 32) {
#pragma unroll
    for (int r2 = 0; r2 < 2; ++r2) {
      int cb = r2 * 256 + w * 64;
      int cidx = cb + lane;
      int row = cidx >> 2, cc = cidx & 3;
      glds16(A  + (size_t)(m0 + row) * 1024 + k0 + cc * 8, Al + (size_t)cb * 8);
      glds16(Wt + (size_t)(n0 + row) * 1024 + k0 + cc * 8, Bl + (size_t)cb * 8);
    }
    __syncthreads();
    bf16x8 af[4], bfv[4];
#pragma unroll
    for (int m = 0; m < 4; ++m)
      af[m] = *reinterpret_cast<const bf16x8*>(Al + (wr * 64 + m * 16 + t) * 32 + g * 8);
#pragma unroll
    for (int n = 0; n < 4; ++n)
      bfv[n] = *reinterpret_cast<const bf16x8*>(Bl + (wc * 64 + n * 16 + t) * 32 + g * 8);
#pragma unroll
    for (int m = 0; m < 4; ++m)
#pragma unroll
      for (int n = 0; n < 4; ++n)
        acc[m][n] = __builtin_amdgcn_mfma_f32_16x16x32_bf16(af[m], bfv[n], acc[m][n], 0, 0, 0);
    __syncthreads();
  }
}

// ---------------- QKV projection GEMM ----------------
// z=0: Q = (x@Wq + bq) * 0.125 * LOG2E -> bf16 (scores land in log2 domain)
// z=1: K =  x@Wk + bk                  -> bf16
// z=2: V =  x@Wv + bv                  -> bf16 transposed Vt[b][n][s]

__global__ __launch_bounds__(256) void gemm_qkv_kernel(
    const bf16_t* __restrict__ A,
    const bf16_t* __restrict__ wtq, const bf16_t* __restrict__ wtk, const bf16_t* __restrict__ wtv,
    const float* __restrict__ bq, const float* __restrict__ bk, const float* __restrict__ bv,
    bf16_t* __restrict__ Qo, bf16_t* __restrict__ Ko, bf16_t* __restrict__ Vt) {
  __shared__ bf16_t Al[128 * 32];
  __shared__ bf16_t Bl[128 * 32];
  int z = blockIdx.z;
  const bf16_t* Wt  = z == 0 ? wtq : z == 1 ? wtk : wtv;
  const float* bias = z == 0 ? bq  : z == 1 ? bk  : bv;
  int m0 = blockIdx.x * 128, n0 = blockIdx.y * 128;
  f32x4 acc[4][4];
  gemm_tile(A, Wt, m0, n0, Al, Bl, acc);

  int tid = threadIdx.x, w = tid >> 6, lane = tid & 63, g = lane >> 4, t = lane & 15;
  int wr = w >> 1, wc = w & 1;
#pragma unroll
  for (int n = 0; n < 4; ++n) {
    int col = n0 + wc * 64 + n * 16 + t;
    float bv_ = bias[col];
#pragma unroll
    for (int m = 0; m < 4; ++m) {
      int row0 = m0 + wr * 64 + m * 16 + g * 4;
      if (z == 2) {
        bf16x4 o;
#pragma unroll
        for (int r = 0; r < 4; ++r) o[r] = (bf16_t)(acc[m][n][r] + bv_);
        *reinterpret_cast<bf16x4*>(Vt + ((size_t)(row0 >> 11) << 21) + (size_t)col * 2048 +
                                   (row0 & 2047)) = o;
      } else {
        float sc = (z == 0) ? (0.125f * LOG2E) : 1.0f;
        bf16_t* O = (z == 0) ? Qo : Ko;
#pragma unroll
        for (int r = 0; r < 4; ++r)
          O[(size_t)(row0 + r) * 1024 + col] = (bf16_t)((acc[m][n][r] + bv_) * sc);
      }
    }
  }
}

// ---------------- output projection GEMM -> fp32 d_out ----------------

__global__ __launch_bounds__(256) void gemm_out_kernel(
    const bf16_t* __restrict__ A, const bf16_t* __restrict__ Wt,
    const float* __restrict__ bias, float* __restrict__ out) {
  __shared__ bf16_t Al[128 * 32];
  __shared__ bf16_t Bl[128 * 32];
  int m0 = blockIdx.x * 128, n0 = blockIdx.y * 128;
  f32x4 acc[4][4];
  gemm_tile(A, Wt, m0, n0, Al, Bl, acc);

  int tid = threadIdx.x, w = tid >> 6, lane = tid & 63, g = lane >> 4, t = lane & 15;
  int wr = w >> 1, wc = w & 1;
#pragma unroll
  for (int n = 0; n < 4; ++n) {
    int col = n0 + wc * 64 + n * 16 + t;
    float bv_ = bias[col];
#pragma unroll
    for (int m = 0; m < 4; ++m) {
      int row0 = m0 + wr * 64 + m * 16 + g * 4;
#pragma unroll
      for (int r = 0; r < 4; ++r)
        out[(size_t)(row0 + r) * 1024 + col] = acc[m][n][r] + bv_;
    }
  }
}

// ---------------- flash attention: swapped-QK at 16x16 (round-1-verified layouts) ----
// grid (S/128, H, B); 4 waves x 32 q-rows (2 subtiles of 16). KV tiles of 64 keys.
// Q pre-scaled by 0.125*LOG2E. K [B,S,H*KD]; Vt [B,H*KD,S]; out Ao [B,S,H*KD] bf16.
// Swapped QK^T: mfma(A=K_frag, B=Q_frag) -> S^T: D col = q = t, D row = key = 4g+r.
// Softmax state per lane for q=t; O accumulator rows are q=4g+r (PV D-layout);
// rescale/normalize factors transposed t->4g+r via __shfl (lane 4g+r).

__global__ __launch_bounds__(256) void attn_kernel(
    const bf16_t* __restrict__ Q, const bf16_t* __restrict__ K,
    const bf16_t* __restrict__ Vt, bf16_t* __restrict__ Ao) {
  __shared__ bf16_t Kl[64 * 64];      // [key][feat]   XOR-swizzled
  __shared__ bf16_t Vl[64 * 64];      // [feat][key]   XOR-swizzled
  __shared__ bf16_t Pl[4][32 * 64];   // per-wave P [qrow 32][key 64] XOR-swizzled

  const int tid = threadIdx.x, w = tid >> 6, lane = tid & 63;
  const int g = lane >> 4, t = lane & 15;
  const int qbase = blockIdx.x * 128, h = blockIdx.y, b = blockIdx.z;
  bf16_t* Plw = Pl[w];

  // Q fragments (B-operand, col-slot = t): qf[qs][kk] = Q[qrow(qs)][32kk + 8g + e]
  bf16x8 qf[2][2];
#pragma unroll
  for (int qs = 0; qs < 2; ++qs) {
    const bf16_t* qp = Q + (size_t)(b * 2048 + qbase + w * 32 + qs * 16 + t) * 1024 + h * 64;
#pragma unroll
    for (int kk = 0; kk < 2; ++kk)
      qf[qs][kk] = *reinterpret_cast<const bf16x8*>(qp + kk * 32 + g * 8);
  }

  f32x4 o[2][4];
#pragma unroll
  for (int qs = 0; qs < 2; ++qs)
#pragma unroll
    for (int n = 0; n < 4; ++n) o[qs][n] = (f32x4){0.f, 0.f, 0.f, 0.f};
  float mq[2] = { -1e30f, -1e30f };
  float lq[2] = { 0.f, 0.f };

  const bf16_t* Kbase = K + (size_t)b * 2048 * 1024 + h * 64;
  const bf16_t* Vbase = Vt + ((size_t)b << 21) + (size_t)(h * 64) * 2048;

  // staging: 256 threads x 2 chunks of 16B per array. chunk c: row=c>>3, col8=c&7.
  const int c0 = tid, c1 = tid + 256;
  const int r0 = c0 >> 3, p0 = c0 & 7, r1 = c1 >> 3, p1 = c1 & 7;
  const int wo0 = swzi(r0, p0 * 16), wo1 = swzi(r1, p1 * 16);
  bf16x8 kst0 = *reinterpret_cast<const bf16x8*>(Kbase + (size_t)r0 * 1024 + p0 * 8);
  bf16x8 kst1 = *reinterpret_cast<const bf16x8*>(Kbase + (size_t)r1 * 1024 + p1 * 8);
  bf16x8 vst0 = *reinterpret_cast<const bf16x8*>(Vbase + (size_t)r0 * 2048 + p0 * 8);
  bf16x8 vst1 = *reinterpret_cast<const bf16x8*>(Vbase + (size_t)r1 * 2048 + p1 * 8);

  for (int jt = 0; jt < 32; ++jt) {
    __syncthreads();                       // all waves done reading previous tile
    *reinterpret_cast<bf16x8*>(Kl + wo0) = kst0;
    *reinterpret_cast<bf16x8*>(Kl + wo1) = kst1;
    *reinterpret_cast<bf16x8*>(Vl + wo0) = vst0;
    *reinterpret_cast<bf16x8*>(Vl + wo1) = vst1;
    __syncthreads();                       // tile visible
    // T14: prefetch next tile into registers (hides HBM latency under compute)
    {
      int jn = ((jt + 1) & 31) * 64;
      kst0 = *reinterpret_cast<const bf16x8*>(Kbase + (size_t)(jn + r0) * 1024 + p0 * 8);
      kst1 = *reinterpret_cast<const bf16x8*>(Kbase + (size_t)(jn + r1) * 1024 + p1 * 8);
      vst0 = *reinterpret_cast<const bf16x8*>(Vbase + (size_t)r0 * 2048 + jn + p0 * 8);
      vst1 = *reinterpret_cast<const bf16x8*>(Vbase + (size_t)r1 * 2048 + jn + p1 * 8);
    }

    // ---- QK^T (swapped): s[qs][c][r] = S[key = 16c + 4g + r][q = t of subtile qs]
    f32x4 s[2][4];
#pragma unroll
    for (int qs = 0; qs < 2; ++qs)
#pragma unroll
      for (int c = 0; c < 4; ++c) s[qs][c] = (f32x4){0.f, 0.f, 0.f, 0.f};
#pragma unroll
    for (int kk = 0; kk < 2; ++kk)
#pragma unroll
      for (int c = 0; c < 4; ++c) {
        bf16x8 kf = *reinterpret_cast<const bf16x8*>(Kl + swzi(16 * c + t, 64 * kk + 16 * g));
        s[0][c] = __builtin_amdgcn_mfma_f32_16x16x32_bf16(kf, qf[0][kk], s[0][c], 0, 0, 0);
        s[1][c] = __builtin_amdgcn_mfma_f32_16x16x32_bf16(kf, qf[1][kk], s[1][c], 0, 0, 0);
      }

    // ---- online softmax per subtile (state in q=t space)
#pragma unroll
    for (int qs = 0; qs < 2; ++qs) {
      float pm = -1e30f;
#pragma unroll
      for (int c = 0; c < 4; ++c) {
        float a0 = fmaxf(s[qs][c][0], s[qs][c][1]);
        float a1 = fmaxf(s[qs][c][2], s[qs][c][3]);
        pm = fmaxf(pm, fmaxf(a0, a1));
      }
      pm = fmaxf(pm, __shfl_xor(pm, 16, 64));
      pm = fmaxf(pm, __shfl_xor(pm, 32, 64));

      // T13 defer-max (log2 domain, THR=8 -> P bounded by 256)
      if (!__all(pm - mq[qs] <= 8.0f)) {
        float mn = fmaxf(mq[qs], pm);
        float corr = __builtin_amdgcn_exp2f(mq[qs] - mn);
        mq[qs] = mn;
        lq[qs] *= corr;
        float cr[4];
#pragma unroll
        for (int r = 0; r < 4; ++r) cr[r] = __shfl(corr, 4 * g + r, 64);
#pragma unroll
        for (int n = 0; n < 4; ++n)
#pragma unroll
          for (int r = 0; r < 4; ++r) o[qs][n][r] *= cr[r];
      }

      // P = exp2(s - m); row-sum; pack to bf16 and store to Pl (4 x b64 writes)
      float rs = 0.f;
#pragma unroll
      for (int c = 0; c < 4; ++c) {
        bf16x4 pw;
#pragma unroll
        for (int r = 0; r < 4; ++r) {
          float e = __builtin_amdgcn_exp2f(s[qs][c][r] - mq[qs]);
          rs += e;
          pw[r] = (bf16_t)e;
        }
        *reinterpret_cast<bf16x4*>(Plw + swzi(qs * 16 + t, 32 * c + 8 * g)) = pw;
      }
      rs += __shfl_xor(rs, 16, 64);
      rs += __shfl_xor(rs, 32, 64);
      lq[qs] += rs;
    }

    // ---- PV: o[qs][n] (+)= P[q][key] * V[key][f]   (round-1-verified read patterns)
#pragma unroll
    for (int kk = 0; kk < 2; ++kk) {
      bf16x8 pa0 = *reinterpret_cast<const bf16x8*>(Plw + swzi(t,      64 * kk + 16 * g));
      bf16x8 pa1 = *reinterpret_cast<const bf16x8*>(Plw + swzi(16 + t, 64 * kk + 16 * g));
#pragma unroll
      for (int n = 0; n < 4; ++n) {
        bf16x8 vbn = *reinterpret_cast<const bf16x8*>(Vl + swzi(16 * n + t, 64 * kk + 16 * g));
        o[0][n] = __builtin_amdgcn_mfma_f32_16x16x32_bf16(pa0, vbn, o[0][n], 0, 0, 0);
        o[1][n] = __builtin_amdgcn_mfma_f32_16x16x32_bf16(pa1, vbn, o[1][n], 0, 0, 0);
      }
    }
  }

  // ---- epilogue: normalize (transpose 1/l from q=t to q=4g+r), store bf16
#pragma unroll
  for (int qs = 0; qs < 2; ++qs) {
    float linv = 1.f / lq[qs];
    float lr[4];
#pragma unroll
    for (int r = 0; r < 4; ++r) lr[r] = __shfl(linv, 4 * g + r, 64);
    bf16_t* op = Ao + (size_t)(b * 2048 + qbase + w * 32 + qs * 16) * 1024 + h * 64;
#pragma unroll
    for (int n = 0; n < 4; ++n)
#pragma unroll
      for (int r = 0; r < 4; ++r)
        op[(size_t)(4 * g + r) * 1024 + 16 * n + t] = (bf16_t)(o[qs][n][r] * lr[r]);
  }
}

// ---------------- launch ----------------

extern "C" void kernel_launch(void* const* d_in, const int* in_sizes, int n_in,
                              void* d_out, int out_size, void* d_ws, size_t ws_size,
                              hipStream_t stream) {
  const float* x  = (const float*)d_in[0];
  const float* Wq = (const float*)d_in[1];
  const float* bq = (const float*)d_in[2];
  const float* Wk = (const float*)d_in[3];
  const float* bk = (const float*)d_in[4];
  const float* Wv = (const float*)d_in[5];
  const float* bv = (const float*)d_in[6];
  const float* Wo = (const float*)d_in[7];
  const float* bo = (const float*)d_in[8];
  float* out = (float*)d_out;
  char* ws = (char*)d_ws;

  bf16_t* xb  = (bf16_t*)(ws);
  bf16_t* wqt = (bf16_t*)(ws + 8388608);
  bf16_t* wkt = (bf16_t*)(ws + 8388608 + 2097152);
  bf16_t* wvt = (bf16_t*)(ws + 8388608 + 2 * 2097152);
  bf16_t* wot = (bf16_t*)(ws + 8388608 + 3 * 2097152);
  bf16_t* Qs  = (bf16_t*)(ws + 16777216);
  bf16_t* Kb  = (bf16_t*)(ws + 16777216 + 8388608);
  bf16_t* Vt  = (bf16_t*)(ws + 16777216 + 2 * 8388608);
  bf16_t* Ao  = (bf16_t*)(ws + 16777216 + 3 * 8388608);

  cast_x_kernel<<<4096, 256, 0, stream>>>(x, xb);
  transpose_w_kernel<<<dim3(16, 16, 4), 256, 0, stream>>>(Wq, Wk, Wv, Wo, wqt, wkt, wvt, wot);
  gemm_qkv_kernel<<<dim3(32, 8, 3), 256, 0, stream>>>(xb, wqt, wkt, wvt, bq, bk, bv, Qs, Kb, Vt);
  attn_kernel<<<dim3(16, 16, 2), 256, 0, stream>>>(Qs, Kb, Vt, Ao);
  gemm_out_kernel<<<dim3(32, 8), 256, 0, stream>>>(Ao, wot, bo, out);
}

// Round 5
// 121.306 us; speedup vs baseline: 1.5227x; 1.0513x over previous
//
#include <hip/hip_runtime.h>
#include <hip/hip_bf16.h>
#include <stdint.h>

typedef __bf16 bf16_t;
typedef __bf16 bf16x8 __attribute__((ext_vector_type(8)));
typedef __bf16 bf16x4 __attribute__((ext_vector_type(4)));
typedef float  f32x4  __attribute__((ext_vector_type(4)));

#define LOG2E 1.44269504088896340736f

// ---------------- helpers ----------------

__device__ __forceinline__ void glds16(const bf16_t* g, bf16_t* l) {
  __builtin_amdgcn_global_load_lds(
      (const __attribute__((address_space(1))) void*)(g),
      (__attribute__((address_space(3))) void*)(l), 16, 0, 0);
}

// XOR-swizzled LDS element index for 128B rows: byte ^= (row&7)<<4.
// Involution + bijective within each row => read(swzi) of write(swzi) is identity.
__device__ __forceinline__ int swzi(int row, int cbyte) {
  return row * 64 + ((cbyte ^ ((row & 7) << 4)) >> 1);
}

// ---------------- cast x: f32 -> bf16 ----------------

__global__ __launch_bounds__(256) void cast_x_kernel(const float* __restrict__ x,
                                                     bf16_t* __restrict__ xb) {
  int i = (blockIdx.x * 256 + threadIdx.x) * 4;
  float4 v = *reinterpret_cast<const float4*>(x + i);
  bf16x4 o = { (bf16_t)v.x, (bf16_t)v.y, (bf16_t)v.z, (bf16_t)v.w };
  *reinterpret_cast<bf16x4*>(xb + i) = o;
}

// ---------------- transpose+cast W[1024][1024] f32 -> Wt[n][k] bf16 ----------------

__global__ __launch_bounds__(256) void transpose_w_kernel(
    const float* __restrict__ W0, const float* __restrict__ W1,
    const float* __restrict__ W2, const float* __restrict__ W3,
    bf16_t* __restrict__ T0, bf16_t* __restrict__ T1,
    bf16_t* __restrict__ T2, bf16_t* __restrict__ T3) {
  const float* W = blockIdx.z == 0 ? W0 : blockIdx.z == 1 ? W1 : blockIdx.z == 2 ? W2 : W3;
  bf16_t*      T = blockIdx.z == 0 ? T0 : blockIdx.z == 1 ? T1 : blockIdx.z == 2 ? T2 : T3;
  __shared__ float tile[64][65];
  int tid = threadIdx.x;
  int k0 = blockIdx.y * 64, n0 = blockIdx.x * 64;
  int rr = tid >> 4, cc = (tid & 15) * 4;
#pragma unroll
  for (int p = 0; p < 4; ++p) {
    float4 v = *reinterpret_cast<const float4*>(W + (size_t)(k0 + p * 16 + rr) * 1024 + n0 + cc);
    tile[p * 16 + rr][cc + 0] = v.x; tile[p * 16 + rr][cc + 1] = v.y;
    tile[p * 16 + rr][cc + 2] = v.z; tile[p * 16 + rr][cc + 3] = v.w;
  }
  __syncthreads();
#pragma unroll
  for (int p = 0; p < 4; ++p) {
    bf16x4 o;
#pragma unroll
    for (int i2 = 0; i2 < 4; ++i2) o[i2] = (bf16_t)tile[cc + i2][p * 16 + rr];
    *reinterpret_cast<bf16x4*>(T + (size_t)(n0 + p * 16 + rr) * 1024 + k0 + cc) = o;
  }
}

// ---------------- shared GEMM main loop: C[128x128] over K=1024 ----------------

__device__ __forceinline__ void gemm_tile(const bf16_t* __restrict__ A,
                                          const bf16_t* __restrict__ Wt,
                                          int m0, int n0,
                                          bf16_t* Al, bf16_t* Bl,
                                          f32x4 acc[4][4]) {
  int tid = threadIdx.x;
  int w = tid >> 6, lane = tid & 63, g = lane >> 4, t = lane & 15;
  int wr = w >> 1, wc = w & 1;
#pragma unroll
  for (int m = 0; m < 4; ++m)
#pragma unroll
    for (int n = 0; n < 4; ++n) acc[m][n] = (f32x4){0.f, 0.f, 0.f, 0.f};

  for (int k0 = 0; k0 < 1024; k0 += 32) {
#pragma unroll
    for (int r2 = 0; r2 < 2; ++r2) {
      int cb = r2 * 256 + w * 64;
      int cidx = cb + lane;
      int row = cidx >> 2, cc = cidx & 3;
      glds16(A  + (size_t)(m0 + row) * 1024 + k0 + cc * 8, Al + (size_t)cb * 8);
      glds16(Wt + (size_t)(n0 + row) * 1024 + k0 + cc * 8, Bl + (size_t)cb * 8);
    }
    __syncthreads();
    bf16x8 af[4], bfv[4];
#pragma unroll
    for (int m = 0; m < 4; ++m)
      af[m] = *reinterpret_cast<const bf16x8*>(Al + (wr * 64 + m * 16 + t) * 32 + g * 8);
#pragma unroll
    for (int n = 0; n < 4; ++n)
      bfv[n] = *reinterpret_cast<const bf16x8*>(Bl + (wc * 64 + n * 16 + t) * 32 + g * 8);
#pragma unroll
    for (int m = 0; m < 4; ++m)
#pragma unroll
      for (int n = 0; n < 4; ++n)
        acc[m][n] = __builtin_amdgcn_mfma_f32_16x16x32_bf16(af[m], bfv[n], acc[m][n], 0, 0, 0);
    __syncthreads();
  }
}

// ---------------- QKV projection GEMM ----------------
// z=0: Q = (x@Wq + bq) * 0.125 * LOG2E -> bf16 (scores land in log2 domain)
// z=1: K =  x@Wk + bk                  -> bf16
// z=2: V =  x@Wv + bv                  -> bf16 transposed Vt[b][n][s]

__global__ __launch_bounds__(256) void gemm_qkv_kernel(
    const bf16_t* __restrict__ A,
    const bf16_t* __restrict__ wtq, const bf16_t* __restrict__ wtk, const bf16_t* __restrict__ wtv,
    const float* __restrict__ bq, const float* __restrict__ bk, const float* __restrict__ bv,
    bf16_t* __restrict__ Qo, bf16_t* __restrict__ Ko, bf16_t* __restrict__ Vt) {
  __shared__ bf16_t Al[128 * 32];
  __shared__ bf16_t Bl[128 * 32];
  int z = blockIdx.z;
  const bf16_t* Wt  = z == 0 ? wtq : z == 1 ? wtk : wtv;
  const float* bias = z == 0 ? bq  : z == 1 ? bk  : bv;
  int m0 = blockIdx.x * 128, n0 = blockIdx.y * 128;
  f32x4 acc[4][4];
  gemm_tile(A, Wt, m0, n0, Al, Bl, acc);

  int tid = threadIdx.x, w = tid >> 6, lane = tid & 63, g = lane >> 4, t = lane & 15;
  int wr = w >> 1, wc = w & 1;
#pragma unroll
  for (int n = 0; n < 4; ++n) {
    int col = n0 + wc * 64 + n * 16 + t;
    float bv_ = bias[col];
#pragma unroll
    for (int m = 0; m < 4; ++m) {
      int row0 = m0 + wr * 64 + m * 16 + g * 4;
      if (z == 2) {
        bf16x4 o;
#pragma unroll
        for (int r = 0; r < 4; ++r) o[r] = (bf16_t)(acc[m][n][r] + bv_);
        *reinterpret_cast<bf16x4*>(Vt + ((size_t)(row0 >> 11) << 21) + (size_t)col * 2048 +
                                   (row0 & 2047)) = o;
      } else {
        float sc = (z == 0) ? (0.125f * LOG2E) : 1.0f;
        bf16_t* O = (z == 0) ? Qo : Ko;
#pragma unroll
        for (int r = 0; r < 4; ++r)
          O[(size_t)(row0 + r) * 1024 + col] = (bf16_t)((acc[m][n][r] + bv_) * sc);
      }
    }
  }
}

// ---------------- output projection GEMM -> fp32 d_out ----------------

__global__ __launch_bounds__(256) void gemm_out_kernel(
    const bf16_t* __restrict__ A, const bf16_t* __restrict__ Wt,
    const float* __restrict__ bias, float* __restrict__ out) {
  __shared__ bf16_t Al[128 * 32];
  __shared__ bf16_t Bl[128 * 32];
  int m0 = blockIdx.x * 128, n0 = blockIdx.y * 128;
  f32x4 acc[4][4];
  gemm_tile(A, Wt, m0, n0, Al, Bl, acc);

  int tid = threadIdx.x, w = tid >> 6, lane = tid & 63, g = lane >> 4, t = lane & 15;
  int wr = w >> 1, wc = w & 1;
#pragma unroll
  for (int n = 0; n < 4; ++n) {
    int col = n0 + wc * 64 + n * 16 + t;
    float bv_ = bias[col];
#pragma unroll
    for (int m = 0; m < 4; ++m) {
      int row0 = m0 + wr * 64 + m * 16 + g * 4;
#pragma unroll
      for (int r = 0; r < 4; ++r)
        out[(size_t)(row0 + r) * 1024 + col] = acc[m][n][r] + bv_;
    }
  }
}

// ---------------- flash attention: swapped-QK at 16x16, 8 waves x 16 q-rows ----------
// grid (S/128, H, B); 512 threads. KV tiles of 64 keys.
// Q pre-scaled by 0.125*LOG2E. K [B,S,H*KD]; Vt [B,H*KD,S]; out Ao [B,S,H*KD] bf16.
// Swapped QK^T: mfma(A=K_frag, B=Q_frag) -> S^T: D col = q = t, D row = key = 4g+r.
// Softmax state per lane for q=t; O accumulator rows are q=4g+r (PV D-layout);
// rescale/normalize factors transposed t->4g+r via __shfl (lane 4g+r).

__global__ __launch_bounds__(512) void attn_kernel(
    const bf16_t* __restrict__ Q, const bf16_t* __restrict__ K,
    const bf16_t* __restrict__ Vt, bf16_t* __restrict__ Ao) {
  __shared__ bf16_t Kl[64 * 64];      // [key][feat]   XOR-swizzled
  __shared__ bf16_t Vl[64 * 64];      // [feat][key]   XOR-swizzled
  __shared__ bf16_t Pl[8][16 * 64];   // per-wave P [qrow 16][key 64] XOR-swizzled

  const int tid = threadIdx.x, w = tid >> 6, lane = tid & 63;
  const int g = lane >> 4, t = lane & 15;
  const int qbase = blockIdx.x * 128, h = blockIdx.y, b = blockIdx.z;
  bf16_t* Plw = Pl[w];

  // Q fragment (B-operand, col-slot = t): qf[kk] = Q[qrow][32kk + 8g + e]
  const bf16_t* qp = Q + (size_t)(b * 2048 + qbase + w * 16 + t) * 1024 + h * 64;
  bf16x8 qf[2];
#pragma unroll
  for (int kk = 0; kk < 2; ++kk)
    qf[kk] = *reinterpret_cast<const bf16x8*>(qp + kk * 32 + g * 8);

  f32x4 o[4];
#pragma unroll
  for (int n = 0; n < 4; ++n) o[n] = (f32x4){0.f, 0.f, 0.f, 0.f};
  float mq = -1e30f, lq = 0.f;

  const bf16_t* Kbase = K + (size_t)b * 2048 * 1024 + h * 64;
  const bf16_t* Vbase = Vt + ((size_t)b << 21) + (size_t)(h * 64) * 2048;

  // staging: 512 threads x exactly 1 chunk of 16B per array (64 rows x 8 chunks)
  const int r0 = tid >> 3, p0 = tid & 7;
  const int wo0 = swzi(r0, p0 * 16);
  bf16x8 kst = *reinterpret_cast<const bf16x8*>(Kbase + (size_t)r0 * 1024 + p0 * 8);
  bf16x8 vst = *reinterpret_cast<const bf16x8*>(Vbase + (size_t)r0 * 2048 + p0 * 8);

  for (int jt = 0; jt < 32; ++jt) {
    __syncthreads();                       // all waves done reading previous tile
    *reinterpret_cast<bf16x8*>(Kl + wo0) = kst;
    *reinterpret_cast<bf16x8*>(Vl + wo0) = vst;
    __syncthreads();                       // tile visible
    // T14: prefetch next tile into registers (hides HBM latency under compute)
    {
      int jn = ((jt + 1) & 31) * 64;
      kst = *reinterpret_cast<const bf16x8*>(Kbase + (size_t)(jn + r0) * 1024 + p0 * 8);
      vst = *reinterpret_cast<const bf16x8*>(Vbase + (size_t)r0 * 2048 + jn + p0 * 8);
    }

    // ---- QK^T (swapped): s[c][r] = S[key = 16c + 4g + r][q = t]
    f32x4 s[4];
#pragma unroll
    for (int c = 0; c < 4; ++c) s[c] = (f32x4){0.f, 0.f, 0.f, 0.f};
#pragma unroll
    for (int kk = 0; kk < 2; ++kk)
#pragma unroll
      for (int c = 0; c < 4; ++c) {
        bf16x8 kf = *reinterpret_cast<const bf16x8*>(Kl + swzi(16 * c + t, 64 * kk + 16 * g));
        s[c] = __builtin_amdgcn_mfma_f32_16x16x32_bf16(kf, qf[kk], s[c], 0, 0, 0);
      }

    // ---- online softmax (state in q=t space)
    float pm = -1e30f;
#pragma unroll
    for (int c = 0; c < 4; ++c) {
      float a0 = fmaxf(s[c][0], s[c][1]);
      float a1 = fmaxf(s[c][2], s[c][3]);
      pm = fmaxf(pm, fmaxf(a0, a1));
    }
    pm = fmaxf(pm, __shfl_xor(pm, 16, 64));
    pm = fmaxf(pm, __shfl_xor(pm, 32, 64));

    // T13 defer-max (log2 domain, THR=8 -> P bounded by 256)
    if (!__all(pm - mq <= 8.0f)) {
      float mn = fmaxf(mq, pm);
      float corr = __builtin_amdgcn_exp2f(mq - mn);
      mq = mn;
      lq *= corr;
      float cr[4];
#pragma unroll
      for (int r = 0; r < 4; ++r) cr[r] = __shfl(corr, 4 * g + r, 64);
#pragma unroll
      for (int n = 0; n < 4; ++n)
#pragma unroll
        for (int r = 0; r < 4; ++r) o[n][r] *= cr[r];
    }

    // P = exp2(s - m); row-sum; pack to bf16 and store to Pl (4 x b64 writes)
    float rs = 0.f;
#pragma unroll
    for (int c = 0; c < 4; ++c) {
      bf16x4 pw;
#pragma unroll
      for (int r = 0; r < 4; ++r) {
        float e = __builtin_amdgcn_exp2f(s[c][r] - mq);
        rs += e;
        pw[r] = (bf16_t)e;
      }
      *reinterpret_cast<bf16x4*>(Plw + swzi(t, 32 * c + 8 * g)) = pw;
    }
    rs += __shfl_xor(rs, 16, 64);
    rs += __shfl_xor(rs, 32, 64);
    lq += rs;

    // ---- PV: o[n] (+)= P[q][key] * V[key][f]
#pragma unroll
    for (int kk = 0; kk < 2; ++kk) {
      bf16x8 pa = *reinterpret_cast<const bf16x8*>(Plw + swzi(t, 64 * kk + 16 * g));
#pragma unroll
      for (int n = 0; n < 4; ++n) {
        bf16x8 vbn = *reinterpret_cast<const bf16x8*>(Vl + swzi(16 * n + t, 64 * kk + 16 * g));
        o[n] = __builtin_amdgcn_mfma_f32_16x16x32_bf16(pa, vbn, o[n], 0, 0, 0);
      }
    }
  }

  // ---- epilogue: normalize (transpose 1/l from q=t to q=4g+r), store bf16
  float linv = 1.f / lq;
  float lr[4];
#pragma unroll
  for (int r = 0; r < 4; ++r) lr[r] = __shfl(linv, 4 * g + r, 64);
  bf16_t* op = Ao + (size_t)(b * 2048 + qbase + w * 16) * 1024 + h * 64;
#pragma unroll
  for (int n = 0; n < 4; ++n)
#pragma unroll
    for (int r = 0; r < 4; ++r)
      op[(size_t)(4 * g + r) * 1024 + 16 * n + t] = (bf16_t)(o[n][r] * lr[r]);
}

// ---------------- launch ----------------

extern "C" void kernel_launch(void* const* d_in, const int* in_sizes, int n_in,
                              void* d_out, int out_size, void* d_ws, size_t ws_size,
                              hipStream_t stream) {
  const float* x  = (const float*)d_in[0];
  const float* Wq = (const float*)d_in[1];
  const float* bq = (const float*)d_in[2];
  const float* Wk = (const float*)d_in[3];
  const float* bk = (const float*)d_in[4];
  const float* Wv = (const float*)d_in[5];
  const float* bv = (const float*)d_in[6];
  const float* Wo = (const float*)d_in[7];
  const float* bo = (const float*)d_in[8];
  float* out = (float*)d_out;
  char* ws = (char*)d_ws;

  bf16_t* xb  = (bf16_t*)(ws);
  bf16_t* wqt = (bf16_t*)(ws + 8388608);
  bf16_t* wkt = (bf16_t*)(ws + 8388608 + 2097152);
  bf16_t* wvt = (bf16_t*)(ws + 8388608 + 2 * 2097152);
  bf16_t* wot = (bf16_t*)(ws + 8388608 + 3 * 2097152);
  bf16_t* Qs  = (bf16_t*)(ws + 16777216);
  bf16_t* Kb  = (bf16_t*)(ws + 16777216 + 8388608);
  bf16_t* Vt  = (bf16_t*)(ws + 16777216 + 2 * 8388608);
  bf16_t* Ao  = (bf16_t*)(ws + 16777216 + 3 * 8388608);

  cast_x_kernel<<<4096, 256, 0, stream>>>(x, xb);
  transpose_w_kernel<<<dim3(16, 16, 4), 256, 0, stream>>>(Wq, Wk, Wv, Wo, wqt, wkt, wvt, wot);
  gemm_qkv_kernel<<<dim3(32, 8, 3), 256, 0, stream>>>(xb, wqt, wkt, wvt, bq, bk, bv, Qs, Kb, Vt);
  attn_kernel<<<dim3(16, 16, 2), 512, 0, stream>>>(Qs, Kb, Vt, Ao);
  gemm_out_kernel<<<dim3(32, 8), 256, 0, stream>>>(Ao, wot, bo, out);
}

// Round 7
// 119.351 us; speedup vs baseline: 1.5477x; 1.0164x over previous
//
#include <hip/hip_runtime.h>
#include <hip/hip_bf16.h>
#include <stdint.h>

typedef __bf16 bf16_t;
typedef __bf16 bf16x8 __attribute__((ext_vector_type(8)));
typedef __bf16 bf16x4 __attribute__((ext_vector_type(4)));
typedef float  f32x4  __attribute__((ext_vector_type(4)));

#define LOG2E 1.44269504088896340736f

// ---------------- helpers ----------------

__device__ __forceinline__ void glds16(const bf16_t* g, bf16_t* l) {
  __builtin_amdgcn_global_load_lds(
      (const __attribute__((address_space(1))) void*)(g),
      (__attribute__((address_space(3))) void*)(l), 16, 0, 0);
}

// XOR-swizzled LDS element index for 128B rows: byte ^= (row&7)<<4.
// Involution + bijective within each row => read(swzi) of write(swzi) is identity.
__device__ __forceinline__ int swzi(int row, int cbyte) {
  return row * 64 + ((cbyte ^ ((row & 7) << 4)) >> 1);
}

// ---------------- fused: transpose+cast 4x W[1024][1024] f32 -> Wt[n][k] bf16 (z<4)
// ----------------        + cast x f32 -> bf16 (z==4) ----------------

__global__ __launch_bounds__(256) void prep_kernel(
    const float* __restrict__ W0, const float* __restrict__ W1,
    const float* __restrict__ W2, const float* __restrict__ W3,
    bf16_t* __restrict__ T0, bf16_t* __restrict__ T1,
    bf16_t* __restrict__ T2, bf16_t* __restrict__ T3,
    const float* __restrict__ x, bf16_t* __restrict__ xb) {
  int tid = threadIdx.x;
  if (blockIdx.z == 4) {
    // cast x: 4,194,304 elems over 256 blocks -> 16384/block -> 16 float4/thread
    int bid = blockIdx.y * 16 + blockIdx.x;
    int base = bid * 16384;
#pragma unroll 4
    for (int i = 0; i < 16; ++i) {
      int idx = base + (i * 256 + tid) * 4;
      float4 v = *reinterpret_cast<const float4*>(x + idx);
      bf16x4 o = { (bf16_t)v.x, (bf16_t)v.y, (bf16_t)v.z, (bf16_t)v.w };
      *reinterpret_cast<bf16x4*>(xb + idx) = o;
    }
    return;
  }
  const float* W = blockIdx.z == 0 ? W0 : blockIdx.z == 1 ? W1 : blockIdx.z == 2 ? W2 : W3;
  bf16_t*      T = blockIdx.z == 0 ? T0 : blockIdx.z == 1 ? T1 : blockIdx.z == 2 ? T2 : T3;
  __shared__ float tile[64][65];
  int k0 = blockIdx.y * 64, n0 = blockIdx.x * 64;
  int rr = tid >> 4, cc = (tid & 15) * 4;
#pragma unroll
  for (int p = 0; p < 4; ++p) {
    float4 v = *reinterpret_cast<const float4*>(W + (size_t)(k0 + p * 16 + rr) * 1024 + n0 + cc);
    tile[p * 16 + rr][cc + 0] = v.x; tile[p * 16 + rr][cc + 1] = v.y;
    tile[p * 16 + rr][cc + 2] = v.z; tile[p * 16 + rr][cc + 3] = v.w;
  }
  __syncthreads();
#pragma unroll
  for (int p = 0; p < 4; ++p) {
    bf16x4 o;
#pragma unroll
    for (int i2 = 0; i2 < 4; ++i2) o[i2] = (bf16_t)tile[cc + i2][p * 16 + rr];
    *reinterpret_cast<bf16x4*>(T + (size_t)(n0 + p * 16 + rr) * 1024 + k0 + cc) = o;
  }
}

// ---------------- shared GEMM main loop: C[128x128] over K=1024 ----------------

__device__ __forceinline__ void gemm_tile(const bf16_t* __restrict__ A,
                                          const bf16_t* __restrict__ Wt,
                                          int m0, int n0,
                                          bf16_t* Al, bf16_t* Bl,
                                          f32x4 acc[4][4]) {
  int tid = threadIdx.x;
  int w = tid >> 6, lane = tid & 63, g = lane >> 4, t = lane & 15;
  int wr = w >> 1, wc = w & 1;
#pragma unroll
  for (int m = 0; m < 4; ++m)
#pragma unroll
    for (int n = 0; n < 4; ++n) acc[m][n] = (f32x4){0.f, 0.f, 0.f, 0.f};

  for (int k0 = 0; k0 < 1024; k0 += 32) {
#pragma unroll
    for (int r2 = 0; r2 < 2; ++r2) {
      int cb = r2 * 256 + w * 64;
      int cidx = cb + lane;
      int row = cidx >> 2, cc = cidx & 3;
      glds16(A  + (size_t)(m0 + row) * 1024 + k0 + cc * 8, Al + (size_t)cb * 8);
      glds16(Wt + (size_t)(n0 + row) * 1024 + k0 + cc * 8, Bl + (size_t)cb * 8);
    }
    __syncthreads();
    bf16x8 af[4], bfv[4];
#pragma unroll
    for (int m = 0; m < 4; ++m)
      af[m] = *reinterpret_cast<const bf16x8*>(Al + (wr * 64 + m * 16 + t) * 32 + g * 8);
#pragma unroll
    for (int n = 0; n < 4; ++n)
      bfv[n] = *reinterpret_cast<const bf16x8*>(Bl + (wc * 64 + n * 16 + t) * 32 + g * 8);
#pragma unroll
    for (int m = 0; m < 4; ++m)
#pragma unroll
      for (int n = 0; n < 4; ++n)
        acc[m][n] = __builtin_amdgcn_mfma_f32_16x16x32_bf16(af[m], bfv[n], acc[m][n], 0, 0, 0);
    __syncthreads();
  }
}

// ---------------- QKV projection GEMM ----------------
// z=0: Q = (x@Wq + bq) * 0.125 * LOG2E -> bf16 (scores land in log2 domain)
// z=1: K =  x@Wk + bk                  -> bf16
// z=2: V =  x@Wv + bv                  -> bf16 transposed Vt[b][n][s]

__global__ __launch_bounds__(256) void gemm_qkv_kernel(
    const bf16_t* __restrict__ A,
    const bf16_t* __restrict__ wtq, const bf16_t* __restrict__ wtk, const bf16_t* __restrict__ wtv,
    const float* __restrict__ bq, const float* __restrict__ bk, const float* __restrict__ bv,
    bf16_t* __restrict__ Qo, bf16_t* __restrict__ Ko, bf16_t* __restrict__ Vt) {
  __shared__ bf16_t Al[128 * 32];
  __shared__ bf16_t Bl[128 * 32];
  int z = blockIdx.z;
  const bf16_t* Wt  = z == 0 ? wtq : z == 1 ? wtk : wtv;
  const float* bias = z == 0 ? bq  : z == 1 ? bk  : bv;
  int m0 = blockIdx.x * 128, n0 = blockIdx.y * 128;
  f32x4 acc[4][4];
  gemm_tile(A, Wt, m0, n0, Al, Bl, acc);

  int tid = threadIdx.x, w = tid >> 6, lane = tid & 63, g = lane >> 4, t = lane & 15;
  int wr = w >> 1, wc = w & 1;
#pragma unroll
  for (int n = 0; n < 4; ++n) {
    int col = n0 + wc * 64 + n * 16 + t;
    float bv_ = bias[col];
#pragma unroll
    for (int m = 0; m < 4; ++m) {
      int row0 = m0 + wr * 64 + m * 16 + g * 4;
      if (z == 2) {
        bf16x4 o;
#pragma unroll
        for (int r = 0; r < 4; ++r) o[r] = (bf16_t)(acc[m][n][r] + bv_);
        *reinterpret_cast<bf16x4*>(Vt + ((size_t)(row0 >> 11) << 21) + (size_t)col * 2048 +
                                   (row0 & 2047)) = o;
      } else {
        float sc = (z == 0) ? (0.125f * LOG2E) : 1.0f;
        bf16_t* O = (z == 0) ? Qo : Ko;
#pragma unroll
        for (int r = 0; r < 4; ++r)
          O[(size_t)(row0 + r) * 1024 + col] = (bf16_t)((acc[m][n][r] + bv_) * sc);
      }
    }
  }
}

// ---------------- output projection GEMM -> fp32 d_out ----------------

__global__ __launch_bounds__(256) void gemm_out_kernel(
    const bf16_t* __restrict__ A, const bf16_t* __restrict__ Wt,
    const float* __restrict__ bias, float* __restrict__ out) {
  __shared__ bf16_t Al[128 * 32];
  __shared__ bf16_t Bl[128 * 32];
  int m0 = blockIdx.x * 128, n0 = blockIdx.y * 128;
  f32x4 acc[4][4];
  gemm_tile(A, Wt, m0, n0, Al, Bl, acc);

  int tid = threadIdx.x, w = tid >> 6, lane = tid & 63, g = lane >> 4, t = lane & 15;
  int wr = w >> 1, wc = w & 1;
#pragma unroll
  for (int n = 0; n < 4; ++n) {
    int col = n0 + wc * 64 + n * 16 + t;
    float bv_ = bias[col];
#pragma unroll
    for (int m = 0; m < 4; ++m) {
      int row0 = m0 + wr * 64 + m * 16 + g * 4;
#pragma unroll
      for (int r = 0; r < 4; ++r)
        out[(size_t)(row0 + r) * 1024 + col] = acc[m][n][r] + bv_;
    }
  }
}

// ---------------- flash attention: swapped-QK 16x16, 8 waves x 16 q, K/V dbuf ------
// grid (S/128, H, B); 512 threads. KV tiles of 64 keys, double-buffered LDS:
// one barrier per tile. Q pre-scaled by 0.125*LOG2E.
// Swapped QK^T: mfma(A=K_frag, B=Q_frag) -> S^T: D col = q = t, D row = key = 4g+r.

__global__ __launch_bounds__(512) void attn_kernel(
    const bf16_t* __restrict__ Q, const bf16_t* __restrict__ K,
    const bf16_t* __restrict__ Vt, bf16_t* __restrict__ Ao) {
  __shared__ bf16_t Kl[2][64 * 64];   // [key][feat]   XOR-swizzled, double-buffered
  __shared__ bf16_t Vl[2][64 * 64];   // [feat][key]   XOR-swizzled, double-buffered
  __shared__ bf16_t Pl[8][16 * 64];   // per-wave P [qrow 16][key 64] XOR-swizzled

  const int tid = threadIdx.x, w = tid >> 6, lane = tid & 63;
  const int g = lane >> 4, t = lane & 15;
  const int qbase = blockIdx.x * 128, h = blockIdx.y, b = blockIdx.z;
  bf16_t* Plw = Pl[w];

  // Q fragment (B-operand, col-slot = t): qf[kk] = Q[qrow][32kk + 8g + e]
  const bf16_t* qp = Q + (size_t)(b * 2048 + qbase + w * 16 + t) * 1024 + h * 64;
  bf16x8 qf[2];
#pragma unroll
  for (int kk = 0; kk < 2; ++kk)
    qf[kk] = *reinterpret_cast<const bf16x8*>(qp + kk * 32 + g * 8);

  f32x4 o[4];
#pragma unroll
  for (int n = 0; n < 4; ++n) o[n] = (f32x4){0.f, 0.f, 0.f, 0.f};
  float mq = -1e30f, lq = 0.f;

  const bf16_t* Kbase = K + (size_t)b * 2048 * 1024 + h * 64;
  const bf16_t* Vbase = Vt + ((size_t)b << 21) + (size_t)(h * 64) * 2048;

  // staging: 512 threads x exactly 1 chunk of 16B per array (64 rows x 8 chunks)
  const int r0 = tid >> 3, p0 = tid & 7;
  const int wo0 = swzi(r0, p0 * 16);

  // prologue: tile 0 -> buf 0 (visible after iter-0 barrier); tile 1 -> regs
  {
    bf16x8 k0v = *reinterpret_cast<const bf16x8*>(Kbase + (size_t)r0 * 1024 + p0 * 8);
    bf16x8 v0v = *reinterpret_cast<const bf16x8*>(Vbase + (size_t)r0 * 2048 + p0 * 8);
    *reinterpret_cast<bf16x8*>(Kl[0] + wo0) = k0v;
    *reinterpret_cast<bf16x8*>(Vl[0] + wo0) = v0v;
  }
  bf16x8 kst = *reinterpret_cast<const bf16x8*>(Kbase + (size_t)(64 + r0) * 1024 + p0 * 8);
  bf16x8 vst = *reinterpret_cast<const bf16x8*>(Vbase + (size_t)r0 * 2048 + 64 + p0 * 8);

  for (int jt = 0; jt < 32; ++jt) {
    const int cur = jt & 1, nxt = cur ^ 1;
    __syncthreads();   // buf[cur] writes visible; all waves done reading buf[nxt] (iter jt-1)
    // write tile jt+1 into buf[nxt] (read next iteration, after its barrier)
    *reinterpret_cast<bf16x8*>(Kl[nxt] + wo0) = kst;
    *reinterpret_cast<bf16x8*>(Vl[nxt] + wo0) = vst;
    // T14: prefetch tile jt+2 into regs (wraps harmlessly at the tail)
    {
      int jn = ((jt + 2) & 31) * 64;
      kst = *reinterpret_cast<const bf16x8*>(Kbase + (size_t)(jn + r0) * 1024 + p0 * 8);
      vst = *reinterpret_cast<const bf16x8*>(Vbase + (size_t)r0 * 2048 + jn + p0 * 8);
    }
    const bf16_t* Kc = Kl[cur];
    const bf16_t* Vc = Vl[cur];

    // ---- QK^T (swapped): s[c][r] = S[key = 16c + 4g + r][q = t]
    f32x4 s[4];
#pragma unroll
    for (int c = 0; c < 4; ++c) s[c] = (f32x4){0.f, 0.f, 0.f, 0.f};
#pragma unroll
    for (int kk = 0; kk < 2; ++kk)
#pragma unroll
      for (int c = 0; c < 4; ++c) {
        bf16x8 kf = *reinterpret_cast<const bf16x8*>(Kc + swzi(16 * c + t, 64 * kk + 16 * g));
        s[c] = __builtin_amdgcn_mfma_f32_16x16x32_bf16(kf, qf[kk], s[c], 0, 0, 0);
      }

    // ---- online softmax (state in q=t space)
    float pm = -1e30f;
#pragma unroll
    for (int c = 0; c < 4; ++c) {
      float a0 = fmaxf(s[c][0], s[c][1]);
      float a1 = fmaxf(s[c][2], s[c][3]);
      pm = fmaxf(pm, fmaxf(a0, a1));
    }
    pm = fmaxf(pm, __shfl_xor(pm, 16, 64));
    pm = fmaxf(pm, __shfl_xor(pm, 32, 64));

    // T13 defer-max (log2 domain, THR=8 -> P bounded by 256)
    if (!__all(pm - mq <= 8.0f)) {
      float mn = fmaxf(mq, pm);
      float corr = __builtin_amdgcn_exp2f(mq - mn);
      mq = mn;
      lq *= corr;
      float cr[4];
#pragma unroll
      for (int r = 0; r < 4; ++r) cr[r] = __shfl(corr, 4 * g + r, 64);
#pragma unroll
      for (int n = 0; n < 4; ++n)
#pragma unroll
        for (int r = 0; r < 4; ++r) o[n][r] *= cr[r];
    }

    // P = exp2(s - m); row-sum; pack to bf16 and store to Pl (4 x b64 writes)
    float rs = 0.f;
#pragma unroll
    for (int c = 0; c < 4; ++c) {
      bf16x4 pw;
#pragma unroll
      for (int r = 0; r < 4; ++r) {
        float e = __builtin_amdgcn_exp2f(s[c][r] - mq);
        rs += e;
        pw[r] = (bf16_t)e;
      }
      *reinterpret_cast<bf16x4*>(Plw + swzi(t, 32 * c + 8 * g)) = pw;
    }
    rs += __shfl_xor(rs, 16, 64);
    rs += __shfl_xor(rs, 32, 64);
    lq += rs;

    // ---- PV: o[n] (+)= P[q][key] * V[key][f]
#pragma unroll
    for (int kk = 0; kk < 2; ++kk) {
      bf16x8 pa = *reinterpret_cast<const bf16x8*>(Plw + swzi(t, 64 * kk + 16 * g));
#pragma unroll
      for (int n = 0; n < 4; ++n) {
        bf16x8 vbn = *reinterpret_cast<const bf16x8*>(Vc + swzi(16 * n + t, 64 * kk + 16 * g));
        o[n] = __builtin_amdgcn_mfma_f32_16x16x32_bf16(pa, vbn, o[n], 0, 0, 0);
      }
    }
  }

  // ---- epilogue: normalize (transpose 1/l from q=t to q=4g+r), store bf16
  float linv = 1.f / lq;
  float lr[4];
#pragma unroll
  for (int r = 0; r < 4; ++r) lr[r] = __shfl(linv, 4 * g + r, 64);
  bf16_t* op = Ao + (size_t)(b * 2048 + qbase + w * 16) * 1024 + h * 64;
#pragma unroll
  for (int n = 0; n < 4; ++n)
#pragma unroll
    for (int r = 0; r < 4; ++r)
      op[(size_t)(4 * g + r) * 1024 + 16 * n + t] = (bf16_t)(o[n][r] * lr[r]);
}

// ---------------- launch ----------------

extern "C" void kernel_launch(void* const* d_in, const int* in_sizes, int n_in,
                              void* d_out, int out_size, void* d_ws, size_t ws_size,
                              hipStream_t stream) {
  const float* x  = (const float*)d_in[0];
  const float* Wq = (const float*)d_in[1];
  const float* bq = (const float*)d_in[2];
  const float* Wk = (const float*)d_in[3];
  const float* bk = (const float*)d_in[4];
  const float* Wv = (const float*)d_in[5];
  const float* bv = (const float*)d_in[6];
  const float* Wo = (const float*)d_in[7];
  const float* bo = (const float*)d_in[8];
  float* out = (float*)d_out;
  char* ws = (char*)d_ws;

  bf16_t* xb  = (bf16_t*)(ws);
  bf16_t* wqt = (bf16_t*)(ws + 8388608);
  bf16_t* wkt = (bf16_t*)(ws + 8388608 + 2097152);
  bf16_t* wvt = (bf16_t*)(ws + 8388608 + 2 * 2097152);
  bf16_t* wot = (bf16_t*)(ws + 8388608 + 3 * 2097152);
  bf16_t* Qs  = (bf16_t*)(ws + 16777216);
  bf16_t* Kb  = (bf16_t*)(ws + 16777216 + 8388608);
  bf16_t* Vt  = (bf16_t*)(ws + 16777216 + 2 * 8388608);
  bf16_t* Ao  = (bf16_t*)(ws + 16777216 + 3 * 8388608);

  prep_kernel<<<dim3(16, 16, 5), 256, 0, stream>>>(Wq, Wk, Wv, Wo, wqt, wkt, wvt, wot, x, xb);
  gemm_qkv_kernel<<<dim3(32, 8, 3), 256, 0, stream>>>(xb, wqt, wkt, wvt, bq, bk, bv, Qs, Kb, Vt);
  attn_kernel<<<dim3(16, 16, 2), 512, 0, stream>>>(Qs, Kb, Vt, Ao);
  gemm_out_kernel<<<dim3(32, 8), 256, 0, stream>>>(Ao, wot, bo, out);
}